// Round 7
// baseline (388.906 us; speedup 1.0000x reference)
//
#include <hip/hip_runtime.h>

#define B_    8
#define N1_   16384
#define N2_   4096
#define NTOT_ (B_ * N1_)

// ---------------------------------------------------------------------------
// GOLD SEMANTICS (verified R12/R13, absmax 0.015625 = bf16 output floor):
//   s  = ((x*x + y*y) + z*z)          plain forward, no fma
//   dot= fma(x,x', fma(y,y', z*z'))   z-first FMA chain (numpy AVX2 einsum)
//   d2 = fma(-2, dot, s1+s2)          bitwise == plain (s1+s2) - 2*dot
//   w  : r = 1/(d2+1e-8), w = r/((r0+r1)+r2), plain f32
// R21: knn (155us, 105% VALU) and the GEMM chain (latency-bound, barriers
// exposed at 1-2 waves/SIMD) are INDEPENDENT until gather and have
// complementary profiles. No streams under graph capture -> heterogeneous
// block fusion: mix1 = gemm1 || knn chunks{0,1}, mix2 = gemm2 || knn
// chunks{2,3}. Role code verbatim from the proven kernels; CU scheduler
// fills gemm stalls with knn VALU work (m114 mechanism, single dispatch).
// LDS union 25.6KB, launch_bounds(256,6) -> 2 gemm + 4 knn blocks/CU.
// ---------------------------------------------------------------------------
__device__ __forceinline__ float np_sumsq(float x, float y, float z)
{
#pragma clang fp contract(off)
    return ((x * x + y * y) + z * z);   // forward, plain (no contraction)
}

// ---------------------------------------------------------------------------
// fused prep: blocks [0,128) fold layer0; [128,192) fold layer1;
// [192,320) pack q4 = (x, y, z, s2) per candidate.
// ---------------------------------------------------------------------------
__global__ __launch_bounds__(256) void prep_kernel(
    const float* __restrict__ W0, const float* __restrict__ b0,
    const float* __restrict__ g0, const float* __restrict__ be0,
    const float* __restrict__ m0, const float* __restrict__ v0,
    const float* __restrict__ W1, const float* __restrict__ b1,
    const float* __restrict__ g1, const float* __restrict__ be1,
    const float* __restrict__ m1, const float* __restrict__ v1,
    const float* __restrict__ p2,
    float* __restrict__ W0p, float* __restrict__ b0p,
    float* __restrict__ W1p, float* __restrict__ b1p,
    float4* __restrict__ q4)
{
    const int bx = blockIdx.x;
    const int tid = threadIdx.x;
    if (bx < 128) {                       // fold layer0: Cout=128, Cin=256
        const int t = bx * 256 + tid;
        const int o = t >> 8;             // /256
        const float s = g0[o] / sqrtf(v0[o] + 1e-5f);
        W0p[t] = W0[t] * s;
        if (t < 128) {
            const float ss = g0[t] / sqrtf(v0[t] + 1e-5f);
            b0p[t] = be0[t] + (b0[t] - m0[t]) * ss;
        }
    } else if (bx < 192) {                // fold layer1: Cout=128, Cin=128
        const int t = (bx - 128) * 256 + tid;
        const int o = t >> 7;             // /128
        const float s = g1[o] / sqrtf(v1[o] + 1e-5f);
        W1p[t] = W1[t] * s;
        if (t < 128) {
            const float ss = g1[t] / sqrtf(v1[t] + 1e-5f);
            b1p[t] = be1[t] + (b1[t] - m1[t]) * ss;
        }
    } else {                              // q4 pack: t < B_*N2_
        const int t = (bx - 192) * 256 + tid;
        const float x = p2[3 * (size_t)t + 0];
        const float y = p2[3 * (size_t)t + 1];
        const float z = p2[3 * (size_t)t + 2];
        q4[t] = make_float4(x, y, z, np_sumsq(x, y, z));
    }
}

// ---------------------------------------------------------------------------
// mix kernel: blocks [0,512) = GEMM role (tile 128M x 64N, acc 8x4, k-order
// identical to the proven kernel -> bit-identical Y); blocks [512,1536) =
// KNN role (R0 scan verbatim), chunks {0,1} in PHASE 1, {2,3} in PHASE 2.
// PHASE 1: Y=h from X=f2 (CIN=256, direct epilogue).
// PHASE 2: Y=f_t from X=h (CIN=128, LDS-transposed epilogue).
// ---------------------------------------------------------------------------
template <int PHASE>
__global__ __launch_bounds__(256, 6) void mix_kernel(
    const float* __restrict__ X, const float* __restrict__ Wp,
    const float* __restrict__ bp, float* __restrict__ Y,
    const float* __restrict__ p1, const float4* __restrict__ q4,
    float* __restrict__ part_d, int* __restrict__ part_i)
{
    constexpr int  CIN   = (PHASE == 1) ? 256 : 128;
    constexpr bool TRANS = (PHASE == 2);

    __shared__ union LdsU {
        struct { float A[32][136]; float B[32][64]; } g;   // 25.6 KB
        float4 qs[1024];                                   // 16 KB
    } lds;

    const int tid = threadIdx.x;
    const int bx  = blockIdx.x;

    if (bx < 512) {
        // ================= GEMM role =================
        const int b  = bx >> 6;
        const int n0 = (bx & 63) * 64;
        const int ty = tid >> 4;          // 0..15 -> M rows
        const int tx = tid & 15;          // 0..15 -> N quad tx*4
        const float* Xb = X + (size_t)b * CIN * N2_;

        float acc[8][4];
#pragma unroll
        for (int i = 0; i < 8; ++i)
#pragma unroll
            for (int j = 0; j < 4; ++j) acc[i][j] = 0.f;

        const int a_kq = (tid & 7) * 4;      // k quad within 32
        const int a_r0 = tid >> 3;           // A row base, +32 per i
        const int b_n4 = (tid & 15) * 4;     // n quad within 64
        const int b_k0 = tid >> 4;           // k row base, +16 per i

        for (int k0 = 0; k0 < CIN; k0 += 32) {
#pragma unroll
            for (int i = 0; i < 4; ++i) {
                const int row = a_r0 + 32 * i;
                const float4 v = *(const float4*)&Wp[(size_t)row * CIN + k0 + a_kq];
                lds.g.A[a_kq + 0][row] = v.x;
                lds.g.A[a_kq + 1][row] = v.y;
                lds.g.A[a_kq + 2][row] = v.z;
                lds.g.A[a_kq + 3][row] = v.w;
            }
#pragma unroll
            for (int i = 0; i < 2; ++i) {
                const int krow = b_k0 + 16 * i;
                *(float4*)&lds.g.B[krow][b_n4] =
                    *(const float4*)&Xb[(size_t)(k0 + krow) * N2_ + n0 + b_n4];
            }
            __syncthreads();

#pragma unroll
            for (int kk = 0; kk < 32; ++kk) {
                const float4 a0 = *(const float4*)&lds.g.A[kk][ty * 4];
                const float4 a1 = *(const float4*)&lds.g.A[kk][64 + ty * 4];
                const float4 bq = *(const float4*)&lds.g.B[kk][tx * 4];
                const float av[8] = {a0.x, a0.y, a0.z, a0.w, a1.x, a1.y, a1.z, a1.w};
                const float bv[4] = {bq.x, bq.y, bq.z, bq.w};
#pragma unroll
                for (int i = 0; i < 8; ++i)
#pragma unroll
                    for (int j = 0; j < 4; ++j)
                        acc[i][j] = fmaf(av[i], bv[j], acc[i][j]);
            }
            __syncthreads();
        }

        float bias_v[8];
#pragma unroll
        for (int i = 0; i < 8; ++i) {
            const int r = (i < 4) ? (ty * 4 + i) : (64 + ty * 4 + (i - 4));
            bias_v[i] = bp[r];
        }

        if (!TRANS) {
#pragma unroll
            for (int i = 0; i < 8; ++i) {
                const int r = (i < 4) ? (ty * 4 + i) : (64 + ty * 4 + (i - 4));
                float* yrow = Y + ((size_t)b * 128 + r) * N2_ + n0;
                float4 v0;
                v0.x = fmaxf(acc[i][0] + bias_v[i], 0.f);
                v0.y = fmaxf(acc[i][1] + bias_v[i], 0.f);
                v0.z = fmaxf(acc[i][2] + bias_v[i], 0.f);
                v0.w = fmaxf(acc[i][3] + bias_v[i], 0.f);
                *(float4*)(yrow + tx * 4) = v0;
            }
        } else {
            // LDS-transposed epilogue: 2 slabs of 32 points; 512B rows.
            float (*T)[132] = (float(*)[132])&lds.g.A[0][0];   // 32x132
#pragma unroll
            for (int s = 0; s < 2; ++s) {
                if ((tx >> 3) == s) {
                    const int cl0 = (tx & 7) * 4;
#pragma unroll
                    for (int i = 0; i < 8; ++i) {
                        const int r = (i < 4) ? (ty * 4 + i) : (64 + ty * 4 + (i - 4));
#pragma unroll
                        for (int j = 0; j < 4; ++j)
                            T[cl0 + j][r] = fmaxf(acc[i][j] + bias_v[i], 0.f);
                    }
                }
                __syncthreads();
#pragma unroll
                for (int p = 0; p < 4; ++p) {
                    const int row = (tid >> 5) + 8 * p;
                    const float4 v = *(const float4*)&T[row][(tid & 31) * 4];
                    float* orow = Y + ((size_t)b * N2_ + n0 + 32 * s + row) * 128;
                    *(float4*)&orow[(tid & 31) * 4] = v;
                }
                __syncthreads();
            }
        }
    } else {
        // ================= KNN role (R0 scan verbatim) =================
        const int bxk = bx - 512;                      // [0, 1024)
        const int chunk = (bxk & 1) + ((PHASE - 1) << 1);
        const int g = (bxk >> 1) * 256 + tid;          // query id
        const int b = g >> 14;                         // uniform per block

        const float px = p1[3 * (size_t)g + 0];
        const float py = p1[3 * (size_t)g + 1];
        const float pz = p1[3 * (size_t)g + 2];
        const float s1 = np_sumsq(px, py, pz);

        const float4* qb = q4 + (size_t)b * N2_ + chunk * 1024;
#pragma unroll
        for (int i = 0; i < 4; ++i) lds.qs[tid + i * 256] = qb[tid + i * 256];
        __syncthreads();

        float d0 = 1e30f, d1 = 1e30f, d2v = 1e30f;
        int i0 = 0, i1 = 0, i2 = 0;
        const int jbase = chunk * 1024;

        for (int j = 0; j < 1024; j += 4) {
#pragma unroll
            for (int u = 0; u < 4; ++u) {
                const float4 q = lds.qs[j + u];
                const float dot = __fmaf_rn(px, q.x, __fmaf_rn(py, q.y, __fmul_rn(pz, q.z)));
                const float ss  = s1 + q.w;
                const float t   = __fmaf_rn(-2.0f, dot, ss);
                if (t < d2v) {
                    const int jj = jbase + j + u;
                    const bool c1 = t < d1, c0 = t < d0;
                    d2v = c1 ? d1 : t;                 i2 = c1 ? i1 : jj;
                    const float nd1 = c1 ? (c0 ? d0 : t) : d1;
                    const int   ni1 = c1 ? (c0 ? i0 : jj) : i1;
                    d1 = nd1;                          i1 = ni1;
                    d0 = c0 ? t : d0;                  i0 = c0 ? jj : i0;
                }
            }
        }

        part_d[(0 * 4 + chunk) * NTOT_ + g] = d0;
        part_d[(1 * 4 + chunk) * NTOT_ + g] = d1;
        part_d[(2 * 4 + chunk) * NTOT_ + g] = d2v;
        part_i[(0 * 4 + chunk) * NTOT_ + g] = i0;
        part_i[(1 * 4 + chunk) * NTOT_ + g] = i1;
        part_i[(2 * 4 + chunk) * NTOT_ + g] = i2;
    }
}

// ---------------------------------------------------------------------------
// gather + merge: per query, stable 12-way merge of chunk partials (gold
// order) + gold plain-f32 weights, then out[b][c][n] = sum_k w_k*f_t[b][ik][c].
// XCD-aligned swizzle: vb = (bx&7)*256 + (bx>>3) -> XCD x handles batch x
// (f_t slice 2.1MB resident in the 4MB XCD L2). Nontemporal output stores.
// ---------------------------------------------------------------------------
__global__ __launch_bounds__(256) void gather_kernel(
    const float* __restrict__ f_t, const float* __restrict__ part_d,
    const int* __restrict__ part_i, float* __restrict__ out)
{
    const int tid = threadIdx.x;
    const int lane = tid & 63, cg = tid >> 6;
    const int vb = (blockIdx.x & 7) * 256 + (blockIdx.x >> 3);  // bijective
    const int g = vb * 64 + lane;
    const int b = g >> 14, n = g & 16383;

    // stable 12-way merge (chunk-major preserves gold tie order)
    float d0 = 1e30f, d1 = 1e30f, d2v = 1e30f;
    int i0 = 0, i1 = 0, i2 = 0;
#pragma unroll
    for (int c = 0; c < 4; ++c) {
#pragma unroll
        for (int k = 0; k < 3; ++k) {
            const float t = part_d[(k * 4 + c) * NTOT_ + g];
            const int  jj = part_i[(k * 4 + c) * NTOT_ + g];
            if (t < d2v) {
                const bool c1 = t < d1, c0 = t < d0;
                d2v = c1 ? d1 : t;                 i2 = c1 ? i1 : jj;
                const float nd1 = c1 ? (c0 ? d0 : t) : d1;
                const int   ni1 = c1 ? (c0 ? i0 : jj) : i1;
                d1 = nd1;                          i1 = ni1;
                d0 = c0 ? t : d0;                  i0 = c0 ? jj : i0;
            }
        }
    }

    float w0, w1, w2;
    {
#pragma clang fp contract(off)
        const float r0 = 1.0f / (d0 + 1e-8f);
        const float r1 = 1.0f / (d1 + 1e-8f);
        const float r2 = 1.0f / (d2v + 1e-8f);
        const float rs = (r0 + r1) + r2;
        w0 = r0 / rs;
        w1 = r1 / rs;
        w2 = r2 / rs;
    }

    const float* base = f_t + (size_t)b * N2_ * 128 + cg * 32;
    const float4* r0v = (const float4*)(base + (size_t)i0 * 128);
    const float4* r1v = (const float4*)(base + (size_t)i1 * 128);
    const float4* r2v = (const float4*)(base + (size_t)i2 * 128);

    float acc[32];
#pragma unroll
    for (int q = 0; q < 8; ++q) {
        const float4 a = r0v[q], bb = r1v[q], c = r2v[q];
        acc[4 * q + 0] = fmaf(w0, a.x, fmaf(w1, bb.x, w2 * c.x));
        acc[4 * q + 1] = fmaf(w0, a.y, fmaf(w1, bb.y, w2 * c.y));
        acc[4 * q + 2] = fmaf(w0, a.z, fmaf(w1, bb.z, w2 * c.z));
        acc[4 * q + 3] = fmaf(w0, a.w, fmaf(w1, bb.w, w2 * c.w));
    }

    float* ob = out + ((size_t)b * 128 + cg * 32) * N1_ + n;
#pragma unroll
    for (int c = 0; c < 32; ++c)
        __builtin_nontemporal_store(acc[c], ob + (size_t)c * N1_);
}

// ---------------------------------------------------------------------------
extern "C" void kernel_launch(void* const* d_in, const int* in_sizes, int n_in,
                              void* d_out, int out_size, void* d_ws, size_t ws_size,
                              hipStream_t stream)
{
    const float* p1  = (const float*)d_in[0];
    const float* p2  = (const float*)d_in[1];
    const float* f2  = (const float*)d_in[2];
    const float* W0  = (const float*)d_in[3];
    const float* b0  = (const float*)d_in[4];
    const float* g0  = (const float*)d_in[5];
    const float* be0 = (const float*)d_in[6];
    const float* m0  = (const float*)d_in[7];
    const float* v0  = (const float*)d_in[8];
    const float* W1  = (const float*)d_in[9];
    const float* b1  = (const float*)d_in[10];
    const float* g1  = (const float*)d_in[11];
    const float* be1 = (const float*)d_in[12];
    const float* m1  = (const float*)d_in[13];
    const float* v1  = (const float*)d_in[14];

    char* ws = (char*)d_ws;
    float4* q4  = (float4*)(ws);                         // 512 KB
    float*  W0p = (float*)(ws + (512 << 10));            // 128 KB
    float*  b0p = (float*)(ws + (640 << 10));            // .5 KB
    float*  W1p = (float*)(ws + (644 << 10));            // 64 KB
    float*  b1p = (float*)(ws + (708 << 10));            // .5 KB
    float*  h   = (float*)(ws + ((size_t)1 << 20));      // 16 MB [B][128][N2]
    float*  f_t = (float*)(ws + ((size_t)17 << 20));     // 16 MB [B][N2][128]
    float*  pd  = (float*)(ws + ((size_t)33 << 20));     // 6.29 MB partials
    int*    pi  = (int*)  (ws + ((size_t)40 << 20));     // 6.29 MB

    prep_kernel<<<320, 256, 0, stream>>>(W0, b0, g0, be0, m0, v0,
                                         W1, b1, g1, be1, m1, v1,
                                         p2, W0p, b0p, W1p, b1p, q4);

    mix_kernel<1><<<1536, 256, 0, stream>>>(f2, W0p, b0p, h,
                                            p1, q4, pd, pi);
    mix_kernel<2><<<1536, 256, 0, stream>>>(h, W1p, b1p, f_t,
                                            p1, q4, pd, pi);

    gather_kernel<<<NTOT_ / 64, 256, 0, stream>>>(f_t, pd, pi, (float*)d_out);
}

// Round 8
// 333.332 us; speedup vs baseline: 1.1667x; 1.1667x over previous
//
#include <hip/hip_runtime.h>

#define B_    8
#define N1_   16384
#define N2_   4096
#define NTOT_ (B_ * N1_)

// ---------------------------------------------------------------------------
// GOLD SEMANTICS (verified R12/R13, absmax 0.015625 = bf16 output floor):
//   s  = ((x*x + y*y) + z*z)          plain forward, no fma
//   dot= fma(x,x', fma(y,y', z*z'))   z-first FMA chain (numpy AVX2 einsum)
//   d2 = fma(-2, dot, s1+s2)          bitwise == plain (s1+s2) - 2*dot
//   w  : r = 1/(d2+1e-8), w = r/((r0+r1)+r2), plain f32
// R22: mix fusion refuted (132 = 77.5 knn-half + full gemm cost; both roles
// VALU-hungry -> no overlap). Tail decomposition from R7: gather ~100-117us,
// gemms ~35-70 combined, prep ~6. Gather's reads are 64-way divergent per
// instruction (random row per lane) -> TA serialization + latency chain.
// This round: coalesced gather. Per-lane merge (unchanged, bit-identical),
// then wave-per-row accumulate: __shfl broadcasts query's w/i; 64 lanes read
// float2 of ONE row per instr (512B contiguous); LDS[64][129] transpose;
// store phase identical coalesced nontemporal 256B rows. Same bytes, same
// arithmetic, divergence-free shape.
// ---------------------------------------------------------------------------
__device__ __forceinline__ float np_sumsq(float x, float y, float z)
{
#pragma clang fp contract(off)
    return ((x * x + y * y) + z * z);   // forward, plain (no contraction)
}

// ---------------------------------------------------------------------------
// fused prep: blocks [0,128) fold layer0; [128,192) fold layer1;
// [192,320) pack q4 = (x, y, z, s2) per candidate.
// ---------------------------------------------------------------------------
__global__ __launch_bounds__(256) void prep_kernel(
    const float* __restrict__ W0, const float* __restrict__ b0,
    const float* __restrict__ g0, const float* __restrict__ be0,
    const float* __restrict__ m0, const float* __restrict__ v0,
    const float* __restrict__ W1, const float* __restrict__ b1,
    const float* __restrict__ g1, const float* __restrict__ be1,
    const float* __restrict__ m1, const float* __restrict__ v1,
    const float* __restrict__ p2,
    float* __restrict__ W0p, float* __restrict__ b0p,
    float* __restrict__ W1p, float* __restrict__ b1p,
    float4* __restrict__ q4)
{
    const int bx = blockIdx.x;
    const int tid = threadIdx.x;
    if (bx < 128) {                       // fold layer0: Cout=128, Cin=256
        const int t = bx * 256 + tid;
        const int o = t >> 8;             // /256
        const float s = g0[o] / sqrtf(v0[o] + 1e-5f);
        W0p[t] = W0[t] * s;
        if (t < 128) {
            const float ss = g0[t] / sqrtf(v0[t] + 1e-5f);
            b0p[t] = be0[t] + (b0[t] - m0[t]) * ss;
        }
    } else if (bx < 192) {                // fold layer1: Cout=128, Cin=128
        const int t = (bx - 128) * 256 + tid;
        const int o = t >> 7;             // /128
        const float s = g1[o] / sqrtf(v1[o] + 1e-5f);
        W1p[t] = W1[t] * s;
        if (t < 128) {
            const float ss = g1[t] / sqrtf(v1[t] + 1e-5f);
            b1p[t] = be1[t] + (b1[t] - m1[t]) * ss;
        }
    } else {                              // q4 pack: t < B_*N2_
        const int t = (bx - 192) * 256 + tid;
        const float x = p2[3 * (size_t)t + 0];
        const float y = p2[3 * (size_t)t + 1];
        const float z = p2[3 * (size_t)t + 2];
        q4[t] = make_float4(x, y, z, np_sumsq(x, y, z));
    }
}

// ---------------------------------------------------------------------------
// f32 tiled GEMM + bias + ReLU.  Y[o][n] = relu( sum_k Wp[o][k] X[k][n] + bp[o] )
// Tile 128M x 64N, acc 8x4, grid 64x8 = 512 blocks = 2 blocks/CU.
// K-accumulation order identical to the proven 128x128 kernel.
// TRANS epilogue: LDS transpose, coalesced 512B rows of f_t.
// ---------------------------------------------------------------------------
template <int CIN, bool TRANS>
__global__ __launch_bounds__(256) void gemm_relu_kernel(
    const float* __restrict__ X, const float* __restrict__ Wp,
    const float* __restrict__ bp, float* __restrict__ Y)
{
    __shared__ float A_lds[32][136];  // [k][m]; reused as T[32][132] in epilogue
    __shared__ float B_lds[32][64];   // [k][n]

    const int b  = blockIdx.y;
    const int n0 = blockIdx.x * 64;
    const int tid = threadIdx.x;
    const int ty = tid >> 4;          // 0..15 -> M rows
    const int tx = tid & 15;          // 0..15 -> N quad tx*4
    const float* Xb = X + (size_t)b * CIN * N2_;

    float acc[8][4];
#pragma unroll
    for (int i = 0; i < 8; ++i)
#pragma unroll
        for (int j = 0; j < 4; ++j) acc[i][j] = 0.f;

    // staging assignments
    const int a_kq = (tid & 7) * 4;      // k quad within 32
    const int a_r0 = tid >> 3;           // A row base, +32 per i
    const int b_n4 = (tid & 15) * 4;     // n quad within 64
    const int b_k0 = tid >> 4;           // k row base, +16 per i

    for (int k0 = 0; k0 < CIN; k0 += 32) {
#pragma unroll
        for (int i = 0; i < 4; ++i) {
            const int row = a_r0 + 32 * i;
            const float4 v = *(const float4*)&Wp[(size_t)row * CIN + k0 + a_kq];
            A_lds[a_kq + 0][row] = v.x;
            A_lds[a_kq + 1][row] = v.y;
            A_lds[a_kq + 2][row] = v.z;
            A_lds[a_kq + 3][row] = v.w;
        }
#pragma unroll
        for (int i = 0; i < 2; ++i) {
            const int krow = b_k0 + 16 * i;
            *(float4*)&B_lds[krow][b_n4] =
                *(const float4*)&Xb[(size_t)(k0 + krow) * N2_ + n0 + b_n4];
        }
        __syncthreads();

#pragma unroll
        for (int kk = 0; kk < 32; ++kk) {
            const float4 a0 = *(const float4*)&A_lds[kk][ty * 4];
            const float4 a1 = *(const float4*)&A_lds[kk][64 + ty * 4];
            const float4 bq = *(const float4*)&B_lds[kk][tx * 4];
            const float av[8] = {a0.x, a0.y, a0.z, a0.w, a1.x, a1.y, a1.z, a1.w};
            const float bv[4] = {bq.x, bq.y, bq.z, bq.w};
#pragma unroll
            for (int i = 0; i < 8; ++i)
#pragma unroll
                for (int j = 0; j < 4; ++j)
                    acc[i][j] = fmaf(av[i], bv[j], acc[i][j]);
        }
        __syncthreads();
    }

    float bias_v[8];
#pragma unroll
    for (int i = 0; i < 8; ++i) {
        const int r = (i < 4) ? (ty * 4 + i) : (64 + ty * 4 + (i - 4));
        bias_v[i] = bp[r];
    }

    if (!TRANS) {
#pragma unroll
        for (int i = 0; i < 8; ++i) {
            const int r = (i < 4) ? (ty * 4 + i) : (64 + ty * 4 + (i - 4));
            float* yrow = Y + ((size_t)b * 128 + r) * N2_ + n0;
            float4 v0;
            v0.x = fmaxf(acc[i][0] + bias_v[i], 0.f);
            v0.y = fmaxf(acc[i][1] + bias_v[i], 0.f);
            v0.z = fmaxf(acc[i][2] + bias_v[i], 0.f);
            v0.w = fmaxf(acc[i][3] + bias_v[i], 0.f);
            *(float4*)(yrow + tx * 4) = v0;
        }
    } else {
        // LDS-transposed epilogue: 2 slabs of 32 points; coalesced 512B rows.
        float (*T)[132] = (float(*)[132])&A_lds[0][0];   // 32x132 <= 32x136
#pragma unroll
        for (int s = 0; s < 2; ++s) {
            if ((tx >> 3) == s) {
                const int cl0 = (tx & 7) * 4;
#pragma unroll
                for (int i = 0; i < 8; ++i) {
                    const int r = (i < 4) ? (ty * 4 + i) : (64 + ty * 4 + (i - 4));
#pragma unroll
                    for (int j = 0; j < 4; ++j)
                        T[cl0 + j][r] = fmaxf(acc[i][j] + bias_v[i], 0.f);
                }
            }
            __syncthreads();
#pragma unroll
            for (int p = 0; p < 4; ++p) {
                const int row = (tid >> 5) + 8 * p;
                const float4 v = *(const float4*)&T[row][(tid & 31) * 4];
                float* orow = Y + ((size_t)b * N2_ + n0 + 32 * s + row) * 128;
                *(float4*)&orow[(tid & 31) * 4] = v;
            }
            __syncthreads();
        }
    }
}

// ---------------------------------------------------------------------------
// KNN phase 1 (R0 verbatim, proven 155.5us @105% VALUBusy): block = 256
// queries x 1 chunk of 1024 candidates; gold d2 scan key; top-3, strict <
// (stable ties, ascending j). Partials out, chunk-major.
// ---------------------------------------------------------------------------
__global__ __launch_bounds__(256, 8) void knn_phase1(
    const float* __restrict__ p1, const float4* __restrict__ q4,
    float* __restrict__ part_d, int* __restrict__ part_i)
{
    __shared__ float4 qs[1024];           // 16 KB
    const int tid = threadIdx.x;
    const int chunk = blockIdx.x & 3;
    const int g = (blockIdx.x >> 2) * 256 + tid;   // query id
    const int b = g >> 14;                         // uniform per block

    const float px = p1[3 * (size_t)g + 0];
    const float py = p1[3 * (size_t)g + 1];
    const float pz = p1[3 * (size_t)g + 2];
    const float s1 = np_sumsq(px, py, pz);

    const float4* qb = q4 + (size_t)b * N2_ + chunk * 1024;
#pragma unroll
    for (int i = 0; i < 4; ++i) qs[tid + i * 256] = qb[tid + i * 256];
    __syncthreads();

    float d0 = 1e30f, d1 = 1e30f, d2v = 1e30f;
    int i0 = 0, i1 = 0, i2 = 0;
    const int jbase = chunk * 1024;

    for (int j = 0; j < 1024; j += 4) {
#pragma unroll
        for (int u = 0; u < 4; ++u) {
            const float4 q = qs[j + u];
            const float dot = __fmaf_rn(px, q.x, __fmaf_rn(py, q.y, __fmul_rn(pz, q.z)));
            const float ss  = s1 + q.w;
            const float t   = __fmaf_rn(-2.0f, dot, ss);
            if (t < d2v) {
                const int jj = jbase + j + u;
                const bool c1 = t < d1, c0 = t < d0;
                d2v = c1 ? d1 : t;                 i2 = c1 ? i1 : jj;
                const float nd1 = c1 ? (c0 ? d0 : t) : d1;
                const int   ni1 = c1 ? (c0 ? i0 : jj) : i1;
                d1 = nd1;                          i1 = ni1;
                d0 = c0 ? t : d0;                  i0 = c0 ? jj : i0;
            }
        }
    }

    part_d[(0 * 4 + chunk) * NTOT_ + g] = d0;
    part_d[(1 * 4 + chunk) * NTOT_ + g] = d1;
    part_d[(2 * 4 + chunk) * NTOT_ + g] = d2v;
    part_i[(0 * 4 + chunk) * NTOT_ + g] = i0;
    part_i[(1 * 4 + chunk) * NTOT_ + g] = i1;
    part_i[(2 * 4 + chunk) * NTOT_ + g] = i2;
}

// ---------------------------------------------------------------------------
// COALESCED gather: block = 64 queries (4 waves).
//  1) per-lane merge of 12 chunk partials (bit-identical to proven merge;
//     lane l <-> query gbase+l; all 4 waves redundant, coalesced loads).
//  2) accumulate: wave w handles queries q=16w..16w+15; __shfl broadcasts
//     that query's w/i from lane q; 64 lanes read float2 of ONE f_t row per
//     instruction (512B contiguous, zero divergence); identical fmaf chain;
//     result to T[q][*] (stride 129: 2-way write, 2-way read aliasing).
//  3) store: out[b][c][n0+lane] = T[lane][c] -- coalesced 256B nontemporal,
//     identical pattern to the proven epilogue.
// XCD-aligned swizzle kept: vb = (bx&7)*256 + (bx>>3) (batch <-> XCD).
// ---------------------------------------------------------------------------
__global__ __launch_bounds__(256) void gather_kernel(
    const float* __restrict__ f_t, const float* __restrict__ part_d,
    const int* __restrict__ part_i, float* __restrict__ out)
{
    __shared__ float T[64][129];          // 33 KB
    const int tid = threadIdx.x;
    const int lane = tid & 63, wv = tid >> 6;
    const int vb = (blockIdx.x & 7) * 256 + (blockIdx.x >> 3);  // bijective
    const int gbase = vb * 64;
    const int g = gbase + lane;
    const int b = g >> 14, n0 = gbase & 16383;

    // ---- 1) per-lane merge (stable 12-way, chunk-major = gold order) ----
    float d0 = 1e30f, d1 = 1e30f, d2v = 1e30f;
    int i0 = 0, i1 = 0, i2 = 0;
#pragma unroll
    for (int c = 0; c < 4; ++c) {
#pragma unroll
        for (int k = 0; k < 3; ++k) {
            const float t = part_d[(k * 4 + c) * NTOT_ + g];
            const int  jj = part_i[(k * 4 + c) * NTOT_ + g];
            if (t < d2v) {
                const bool c1 = t < d1, c0 = t < d0;
                d2v = c1 ? d1 : t;                 i2 = c1 ? i1 : jj;
                const float nd1 = c1 ? (c0 ? d0 : t) : d1;
                const int   ni1 = c1 ? (c0 ? i0 : jj) : i1;
                d1 = nd1;                          i1 = ni1;
                d0 = c0 ? t : d0;                  i0 = c0 ? jj : i0;
            }
        }
    }

    float w0, w1, w2;
    {
#pragma clang fp contract(off)
        const float r0 = 1.0f / (d0 + 1e-8f);
        const float r1 = 1.0f / (d1 + 1e-8f);
        const float r2 = 1.0f / (d2v + 1e-8f);
        const float rs = (r0 + r1) + r2;
        w0 = r0 / rs;
        w1 = r1 / rs;
        w2 = r2 / rs;
    }

    // ---- 2) accumulate: wave wv owns queries q = 16*wv .. 16*wv+15 ----
    const float* fb = f_t + (size_t)b * N2_ * 128;
#pragma unroll
    for (int j = 0; j < 16; ++j) {
        const int q = wv * 16 + j;
        const int   qi0 = __shfl(i0, q);
        const int   qi1 = __shfl(i1, q);
        const int   qi2 = __shfl(i2, q);
        const float qw0 = __shfl(w0, q);
        const float qw1 = __shfl(w1, q);
        const float qw2 = __shfl(w2, q);
        const float2 a  = *(const float2*)(fb + (size_t)qi0 * 128 + 2 * lane);
        const float2 bb = *(const float2*)(fb + (size_t)qi1 * 128 + 2 * lane);
        const float2 c  = *(const float2*)(fb + (size_t)qi2 * 128 + 2 * lane);
        T[q][2 * lane + 0] = fmaf(qw0, a.x, fmaf(qw1, bb.x, qw2 * c.x));
        T[q][2 * lane + 1] = fmaf(qw0, a.y, fmaf(qw1, bb.y, qw2 * c.y));
    }
    __syncthreads();

    // ---- 3) transpose store: wave wv -> channels 32*wv .. 32*wv+31 ----
    float* ob = out + ((size_t)b * 128) * N1_ + n0 + lane;
#pragma unroll
    for (int ci = 0; ci < 32; ++ci) {
        const int cch = wv * 32 + ci;
        __builtin_nontemporal_store(T[lane][cch], ob + (size_t)cch * N1_);
    }
}

// ---------------------------------------------------------------------------
extern "C" void kernel_launch(void* const* d_in, const int* in_sizes, int n_in,
                              void* d_out, int out_size, void* d_ws, size_t ws_size,
                              hipStream_t stream)
{
    const float* p1  = (const float*)d_in[0];
    const float* p2  = (const float*)d_in[1];
    const float* f2  = (const float*)d_in[2];
    const float* W0  = (const float*)d_in[3];
    const float* b0  = (const float*)d_in[4];
    const float* g0  = (const float*)d_in[5];
    const float* be0 = (const float*)d_in[6];
    const float* m0  = (const float*)d_in[7];
    const float* v0  = (const float*)d_in[8];
    const float* W1  = (const float*)d_in[9];
    const float* b1  = (const float*)d_in[10];
    const float* g1  = (const float*)d_in[11];
    const float* be1 = (const float*)d_in[12];
    const float* m1  = (const float*)d_in[13];
    const float* v1  = (const float*)d_in[14];

    char* ws = (char*)d_ws;
    float4* q4  = (float4*)(ws);                         // 512 KB
    float*  W0p = (float*)(ws + (512 << 10));            // 128 KB
    float*  b0p = (float*)(ws + (640 << 10));            // .5 KB
    float*  W1p = (float*)(ws + (644 << 10));            // 64 KB
    float*  b1p = (float*)(ws + (708 << 10));            // .5 KB
    float*  h   = (float*)(ws + ((size_t)1 << 20));      // 16 MB [B][128][N2] (dead after gemm2)
    float*  f_t = (float*)(ws + ((size_t)17 << 20));     // 16 MB [B][N2][128]
    // KNN partials reuse h's region (dead once gemm2 has run):
    float*  pd  = (float*)(ws + ((size_t)1 << 20));      // 6.29 MB
    int*    pi  = (int*)  (ws + ((size_t)9 << 20));      // 6.29 MB

    prep_kernel<<<320, 256, 0, stream>>>(W0, b0, g0, be0, m0, v0,
                                         W1, b1, g1, be1, m1, v1,
                                         p2, W0p, b0p, W1p, b1p, q4);

    gemm_relu_kernel<256, false><<<dim3(64, 8), 256, 0, stream>>>(f2, W0p, b0p, h);
    gemm_relu_kernel<128, true ><<<dim3(64, 8), 256, 0, stream>>>(h, W1p, b1p, f_t);

    knn_phase1<<<(NTOT_ / 256) * 4, 256, 0, stream>>>(p1, q4, pd, pi);
    gather_kernel<<<NTOT_ / 64, 256, 0, stream>>>(f_t, pd, pi, (float*)d_out);
}

// Round 9
// 325.161 us; speedup vs baseline: 1.1960x; 1.0251x over previous
//
#include <hip/hip_runtime.h>

#define B_    8
#define N1_   16384
#define N2_   4096
#define NTOT_ (B_ * N1_)

// ---------------------------------------------------------------------------
// GOLD SEMANTICS (verified R12/R13, absmax 0.015625 = bf16 output floor):
//   s  = ((x*x + y*y) + z*z)          plain forward, no fma
//   dot= fma(x,x', fma(y,y', z*z'))   z-first FMA chain (numpy AVX2 einsum)
//   d2 = fma(-2, dot, s1+s2)          bitwise == plain (s1+s2) - 2*dot
//   w  : r = 1/(d2+1e-8), w = r/((r0+r1)+r2), plain f32
// R23: gather coalescing won (-21us). Now the GEMM pair (~75-90us est from
// R7 decomposition): (a) fuse gemm1+gemm2 through LDS -- gemm1's block tile
// IS gemm2's B tile; h never touches HBM (saves 32MB round-trip + gemm2
// B-staging latency + a launch). (b) restore 8x8 thread-tiles (128x128
// block): R6's 8x4 re-tile broke LDS-pipe balance (48B LDS per 64
// fma-cycles; LDS pipe over-subscribed at 8 waves/CU). 8x8 = 64B/128cy =
// parity; LDS and VALU pipes overlap. Identical k-order / fmaf chains /
// epilogues => bit-identical f_t. knn (R0 verbatim) + coalesced gather kept.
// ---------------------------------------------------------------------------
__device__ __forceinline__ float np_sumsq(float x, float y, float z)
{
#pragma clang fp contract(off)
    return ((x * x + y * y) + z * z);   // forward, plain (no contraction)
}

// ---------------------------------------------------------------------------
// fused prep: blocks [0,128) fold layer0; [128,192) fold layer1;
// [192,320) pack q4 = (x, y, z, s2) per candidate.
// ---------------------------------------------------------------------------
__global__ __launch_bounds__(256) void prep_kernel(
    const float* __restrict__ W0, const float* __restrict__ b0,
    const float* __restrict__ g0, const float* __restrict__ be0,
    const float* __restrict__ m0, const float* __restrict__ v0,
    const float* __restrict__ W1, const float* __restrict__ b1,
    const float* __restrict__ g1, const float* __restrict__ be1,
    const float* __restrict__ m1, const float* __restrict__ v1,
    const float* __restrict__ p2,
    float* __restrict__ W0p, float* __restrict__ b0p,
    float* __restrict__ W1p, float* __restrict__ b1p,
    float4* __restrict__ q4)
{
    const int bx = blockIdx.x;
    const int tid = threadIdx.x;
    if (bx < 128) {                       // fold layer0: Cout=128, Cin=256
        const int t = bx * 256 + tid;
        const int o = t >> 8;             // /256
        const float s = g0[o] / sqrtf(v0[o] + 1e-5f);
        W0p[t] = W0[t] * s;
        if (t < 128) {
            const float ss = g0[t] / sqrtf(v0[t] + 1e-5f);
            b0p[t] = be0[t] + (b0[t] - m0[t]) * ss;
        }
    } else if (bx < 192) {                // fold layer1: Cout=128, Cin=128
        const int t = (bx - 128) * 256 + tid;
        const int o = t >> 7;             // /128
        const float s = g1[o] / sqrtf(v1[o] + 1e-5f);
        W1p[t] = W1[t] * s;
        if (t < 128) {
            const float ss = g1[t] / sqrtf(v1[t] + 1e-5f);
            b1p[t] = be1[t] + (b1[t] - m1[t]) * ss;
        }
    } else {                              // q4 pack: t < B_*N2_
        const int t = (bx - 192) * 256 + tid;
        const float x = p2[3 * (size_t)t + 0];
        const float y = p2[3 * (size_t)t + 1];
        const float z = p2[3 * (size_t)t + 2];
        q4[t] = make_float4(x, y, z, np_sumsq(x, y, z));
    }
}

// ---------------------------------------------------------------------------
// FUSED double GEMM + bias + ReLU.  Per block (batch b, 128 N-cols):
//   phase A: h_tile = relu(W0p @ f2_tile + b0p)      (K=256, global B)
//   phase B: f_t    = relu(W1p @ h_tile + b1p)^T     (K=128, B from LDS)
// 128M x 128N tiles, 8x8 acc (LDS/VALU pipe parity), grid 32x8.
// B_lds aliases HT's head: B dead before HT is written (trailing barrier of
// the phase-A k-loop guards). HT stride 132 floats: 16B-aligned rows,
// 2-way (free) bank aliasing. K-order / fmaf order == proven kernels.
// ---------------------------------------------------------------------------
__global__ __launch_bounds__(256) void gemm_fused_kernel(
    const float* __restrict__ f2, const float* __restrict__ W0p,
    const float* __restrict__ b0p, const float* __restrict__ W1p,
    const float* __restrict__ b1p, float* __restrict__ f_t)
{
    __shared__ float A_lds[32][136];      // 17.4 KB: A-stage (A,B phases) + T
    __shared__ float HT[128][132];        // 67.6 KB: h tile; head aliases B_lds
    float (*B_lds)[128] = (float(*)[128])&HT[0][0];   // [32][128] = 16 KB

    const int b  = blockIdx.y;
    const int n0 = blockIdx.x * 128;
    const int tid = threadIdx.x;
    const int ty = tid >> 4;
    const int tx = tid & 15;

    float acc[8][8];

    // staging assignments (verbatim proven kernel)
    const int a_kq = (tid & 7) * 4;      // k quad within 32
    const int a_r0 = tid >> 3;           // A row base, +32 per i
    const int b_n4 = (tid & 31) * 4;     // n quad (32 thr = 512B/row)
    const int b_k0 = tid >> 5;           // k row base, +8 per i

    // ================= phase A: h_tile = relu(W0p @ f2 + b0p) =============
#pragma unroll
    for (int i = 0; i < 8; ++i)
#pragma unroll
        for (int j = 0; j < 8; ++j) acc[i][j] = 0.f;

    {
        const float* Xb = f2 + (size_t)b * 256 * N2_;
        for (int k0 = 0; k0 < 256; k0 += 32) {
#pragma unroll
            for (int i = 0; i < 4; ++i) {
                const int row = a_r0 + 32 * i;
                const float4 v = *(const float4*)&W0p[(size_t)row * 256 + k0 + a_kq];
                A_lds[a_kq + 0][row] = v.x;
                A_lds[a_kq + 1][row] = v.y;
                A_lds[a_kq + 2][row] = v.z;
                A_lds[a_kq + 3][row] = v.w;
            }
#pragma unroll
            for (int i = 0; i < 4; ++i) {
                const int krow = b_k0 + 8 * i;
                *(float4*)&B_lds[krow][b_n4] =
                    *(const float4*)&Xb[(size_t)(k0 + krow) * N2_ + n0 + b_n4];
            }
            __syncthreads();

#pragma unroll
            for (int kk = 0; kk < 32; ++kk) {
                const float4 a0 = *(const float4*)&A_lds[kk][ty * 4];
                const float4 a1 = *(const float4*)&A_lds[kk][64 + ty * 4];
                const float4 bq0 = *(const float4*)&B_lds[kk][tx * 4];
                const float4 bq1 = *(const float4*)&B_lds[kk][64 + tx * 4];
                const float av[8] = {a0.x, a0.y, a0.z, a0.w, a1.x, a1.y, a1.z, a1.w};
                const float bv[8] = {bq0.x, bq0.y, bq0.z, bq0.w, bq1.x, bq1.y, bq1.z, bq1.w};
#pragma unroll
                for (int i = 0; i < 8; ++i)
#pragma unroll
                    for (int j = 0; j < 8; ++j)
                        acc[i][j] = fmaf(av[i], bv[j], acc[i][j]);
            }
            __syncthreads();
        }
    }

    // h epilogue -> LDS (bias + relu), bit-identical values to old gemm1
    {
        float bias_v[8];
#pragma unroll
        for (int i = 0; i < 8; ++i) {
            const int r = (i < 4) ? (ty * 4 + i) : (64 + ty * 4 + (i - 4));
            bias_v[i] = b0p[r];
        }
#pragma unroll
        for (int i = 0; i < 8; ++i) {
            const int r = (i < 4) ? (ty * 4 + i) : (64 + ty * 4 + (i - 4));
            float4 v0, v1;
            v0.x = fmaxf(acc[i][0] + bias_v[i], 0.f);
            v0.y = fmaxf(acc[i][1] + bias_v[i], 0.f);
            v0.z = fmaxf(acc[i][2] + bias_v[i], 0.f);
            v0.w = fmaxf(acc[i][3] + bias_v[i], 0.f);
            v1.x = fmaxf(acc[i][4] + bias_v[i], 0.f);
            v1.y = fmaxf(acc[i][5] + bias_v[i], 0.f);
            v1.z = fmaxf(acc[i][6] + bias_v[i], 0.f);
            v1.w = fmaxf(acc[i][7] + bias_v[i], 0.f);
            *(float4*)&HT[r][tx * 4] = v0;
            *(float4*)&HT[r][64 + tx * 4] = v1;
        }
    }
    // NOTE: no barrier needed yet; first phase-B barrier below guards HT.

    // ================= phase B: out = relu(W1p @ h_tile + b1p) ============
#pragma unroll
    for (int i = 0; i < 8; ++i)
#pragma unroll
        for (int j = 0; j < 8; ++j) acc[i][j] = 0.f;

    for (int k0 = 0; k0 < 128; k0 += 32) {
#pragma unroll
        for (int i = 0; i < 4; ++i) {
            const int row = a_r0 + 32 * i;
            const float4 v = *(const float4*)&W1p[(size_t)row * 128 + k0 + a_kq];
            A_lds[a_kq + 0][row] = v.x;
            A_lds[a_kq + 1][row] = v.y;
            A_lds[a_kq + 2][row] = v.z;
            A_lds[a_kq + 3][row] = v.w;
        }
        __syncthreads();   // guards HT writes (k0=0) + A_lds staging

#pragma unroll
        for (int kk = 0; kk < 32; ++kk) {
            const float4 a0 = *(const float4*)&A_lds[kk][ty * 4];
            const float4 a1 = *(const float4*)&A_lds[kk][64 + ty * 4];
            const float4 bq0 = *(const float4*)&HT[k0 + kk][tx * 4];
            const float4 bq1 = *(const float4*)&HT[k0 + kk][64 + tx * 4];
            const float av[8] = {a0.x, a0.y, a0.z, a0.w, a1.x, a1.y, a1.z, a1.w};
            const float bv[8] = {bq0.x, bq0.y, bq0.z, bq0.w, bq1.x, bq1.y, bq1.z, bq1.w};
#pragma unroll
            for (int i = 0; i < 8; ++i)
#pragma unroll
                for (int j = 0; j < 8; ++j)
                    acc[i][j] = fmaf(av[i], bv[j], acc[i][j]);
        }
        __syncthreads();
    }

    // TRANS epilogue (verbatim proven): 4 slabs of 32 points; 512B rows.
    {
        float bias_v[8];
#pragma unroll
        for (int i = 0; i < 8; ++i) {
            const int r = (i < 4) ? (ty * 4 + i) : (64 + ty * 4 + (i - 4));
            bias_v[i] = b1p[r];
        }
        float (*T)[132] = (float(*)[132])&A_lds[0][0];   // 32x132 <= 32x136
#pragma unroll
        for (int s = 0; s < 4; ++s) {
            if ((tx >> 3) == (s & 1)) {
                const int joff = (s >> 1) * 4;
                const int cl0 = (tx & 7) * 4;
#pragma unroll
                for (int i = 0; i < 8; ++i) {
                    const int r = (i < 4) ? (ty * 4 + i) : (64 + ty * 4 + (i - 4));
#pragma unroll
                    for (int j = 0; j < 4; ++j)
                        T[cl0 + j][r] = fmaxf(acc[i][j + joff] + bias_v[i], 0.f);
                }
            }
            __syncthreads();
#pragma unroll
            for (int p = 0; p < 4; ++p) {
                const int row = (tid >> 5) + 8 * p;
                const float4 v = *(const float4*)&T[row][(tid & 31) * 4];
                float* orow = f_t + ((size_t)b * N2_ + n0 + 32 * s + row) * 128;
                *(float4*)&orow[(tid & 31) * 4] = v;
            }
            __syncthreads();
        }
    }
}

// ---------------------------------------------------------------------------
// KNN phase 1 (R0 verbatim, proven 155.5us @105% VALUBusy): block = 256
// queries x 1 chunk of 1024 candidates; gold d2 scan key; top-3, strict <
// (stable ties, ascending j). Partials out, chunk-major.
// ---------------------------------------------------------------------------
__global__ __launch_bounds__(256, 8) void knn_phase1(
    const float* __restrict__ p1, const float4* __restrict__ q4,
    float* __restrict__ part_d, int* __restrict__ part_i)
{
    __shared__ float4 qs[1024];           // 16 KB
    const int tid = threadIdx.x;
    const int chunk = blockIdx.x & 3;
    const int g = (blockIdx.x >> 2) * 256 + tid;   // query id
    const int b = g >> 14;                         // uniform per block

    const float px = p1[3 * (size_t)g + 0];
    const float py = p1[3 * (size_t)g + 1];
    const float pz = p1[3 * (size_t)g + 2];
    const float s1 = np_sumsq(px, py, pz);

    const float4* qb = q4 + (size_t)b * N2_ + chunk * 1024;
#pragma unroll
    for (int i = 0; i < 4; ++i) qs[tid + i * 256] = qb[tid + i * 256];
    __syncthreads();

    float d0 = 1e30f, d1 = 1e30f, d2v = 1e30f;
    int i0 = 0, i1 = 0, i2 = 0;
    const int jbase = chunk * 1024;

    for (int j = 0; j < 1024; j += 4) {
#pragma unroll
        for (int u = 0; u < 4; ++u) {
            const float4 q = qs[j + u];
            const float dot = __fmaf_rn(px, q.x, __fmaf_rn(py, q.y, __fmul_rn(pz, q.z)));
            const float ss  = s1 + q.w;
            const float t   = __fmaf_rn(-2.0f, dot, ss);
            if (t < d2v) {
                const int jj = jbase + j + u;
                const bool c1 = t < d1, c0 = t < d0;
                d2v = c1 ? d1 : t;                 i2 = c1 ? i1 : jj;
                const float nd1 = c1 ? (c0 ? d0 : t) : d1;
                const int   ni1 = c1 ? (c0 ? i0 : jj) : i1;
                d1 = nd1;                          i1 = ni1;
                d0 = c0 ? t : d0;                  i0 = c0 ? jj : i0;
            }
        }
    }

    part_d[(0 * 4 + chunk) * NTOT_ + g] = d0;
    part_d[(1 * 4 + chunk) * NTOT_ + g] = d1;
    part_d[(2 * 4 + chunk) * NTOT_ + g] = d2v;
    part_i[(0 * 4 + chunk) * NTOT_ + g] = i0;
    part_i[(1 * 4 + chunk) * NTOT_ + g] = i1;
    part_i[(2 * 4 + chunk) * NTOT_ + g] = i2;
}

// ---------------------------------------------------------------------------
// COALESCED gather (R22, proven -21us): block = 64 queries (4 waves).
//  1) per-lane merge of 12 chunk partials (bit-identical gold order+weights)
//  2) wave-per-row accumulate: __shfl broadcasts (w,i); 64 lanes read float2
//     of ONE f_t row per instr (512B contiguous); LDS[64][129] transpose.
//  3) coalesced 256B nontemporal channel-row stores.
// XCD-aligned swizzle: vb = (bx&7)*256 + (bx>>3) (batch <-> XCD).
// ---------------------------------------------------------------------------
__global__ __launch_bounds__(256) void gather_kernel(
    const float* __restrict__ f_t, const float* __restrict__ part_d,
    const int* __restrict__ part_i, float* __restrict__ out)
{
    __shared__ float T[64][129];          // 33 KB
    const int tid = threadIdx.x;
    const int lane = tid & 63, wv = tid >> 6;
    const int vb = (blockIdx.x & 7) * 256 + (blockIdx.x >> 3);  // bijective
    const int gbase = vb * 64;
    const int g = gbase + lane;
    const int b = g >> 14, n0 = gbase & 16383;

    // ---- 1) per-lane merge (stable 12-way, chunk-major = gold order) ----
    float d0 = 1e30f, d1 = 1e30f, d2v = 1e30f;
    int i0 = 0, i1 = 0, i2 = 0;
#pragma unroll
    for (int c = 0; c < 4; ++c) {
#pragma unroll
        for (int k = 0; k < 3; ++k) {
            const float t = part_d[(k * 4 + c) * NTOT_ + g];
            const int  jj = part_i[(k * 4 + c) * NTOT_ + g];
            if (t < d2v) {
                const bool c1 = t < d1, c0 = t < d0;
                d2v = c1 ? d1 : t;                 i2 = c1 ? i1 : jj;
                const float nd1 = c1 ? (c0 ? d0 : t) : d1;
                const int   ni1 = c1 ? (c0 ? i0 : jj) : i1;
                d1 = nd1;                          i1 = ni1;
                d0 = c0 ? t : d0;                  i0 = c0 ? jj : i0;
            }
        }
    }

    float w0, w1, w2;
    {
#pragma clang fp contract(off)
        const float r0 = 1.0f / (d0 + 1e-8f);
        const float r1 = 1.0f / (d1 + 1e-8f);
        const float r2 = 1.0f / (d2v + 1e-8f);
        const float rs = (r0 + r1) + r2;
        w0 = r0 / rs;
        w1 = r1 / rs;
        w2 = r2 / rs;
    }

    // ---- 2) accumulate: wave wv owns queries q = 16*wv .. 16*wv+15 ----
    const float* fb = f_t + (size_t)b * N2_ * 128;
#pragma unroll
    for (int j = 0; j < 16; ++j) {
        const int q = wv * 16 + j;
        const int   qi0 = __shfl(i0, q);
        const int   qi1 = __shfl(i1, q);
        const int   qi2 = __shfl(i2, q);
        const float qw0 = __shfl(w0, q);
        const float qw1 = __shfl(w1, q);
        const float qw2 = __shfl(w2, q);
        const float2 a  = *(const float2*)(fb + (size_t)qi0 * 128 + 2 * lane);
        const float2 bb = *(const float2*)(fb + (size_t)qi1 * 128 + 2 * lane);
        const float2 c  = *(const float2*)(fb + (size_t)qi2 * 128 + 2 * lane);
        T[q][2 * lane + 0] = fmaf(qw0, a.x, fmaf(qw1, bb.x, qw2 * c.x));
        T[q][2 * lane + 1] = fmaf(qw0, a.y, fmaf(qw1, bb.y, qw2 * c.y));
    }
    __syncthreads();

    // ---- 3) transpose store: wave wv -> channels 32*wv .. 32*wv+31 ----
    float* ob = out + ((size_t)b * 128) * N1_ + n0 + lane;
#pragma unroll
    for (int ci = 0; ci < 32; ++ci) {
        const int cch = wv * 32 + ci;
        __builtin_nontemporal_store(T[lane][cch], ob + (size_t)cch * N1_);
    }
}

// ---------------------------------------------------------------------------
extern "C" void kernel_launch(void* const* d_in, const int* in_sizes, int n_in,
                              void* d_out, int out_size, void* d_ws, size_t ws_size,
                              hipStream_t stream)
{
    const float* p1  = (const float*)d_in[0];
    const float* p2  = (const float*)d_in[1];
    const float* f2  = (const float*)d_in[2];
    const float* W0  = (const float*)d_in[3];
    const float* b0  = (const float*)d_in[4];
    const float* g0  = (const float*)d_in[5];
    const float* be0 = (const float*)d_in[6];
    const float* m0  = (const float*)d_in[7];
    const float* v0  = (const float*)d_in[8];
    const float* W1  = (const float*)d_in[9];
    const float* b1  = (const float*)d_in[10];
    const float* g1  = (const float*)d_in[11];
    const float* be1 = (const float*)d_in[12];
    const float* m1  = (const float*)d_in[13];
    const float* v1  = (const float*)d_in[14];

    char* ws = (char*)d_ws;
    float4* q4  = (float4*)(ws);                         // 512 KB
    float*  W0p = (float*)(ws + (512 << 10));            // 128 KB
    float*  b0p = (float*)(ws + (640 << 10));            // .5 KB
    float*  W1p = (float*)(ws + (644 << 10));            // 64 KB
    float*  b1p = (float*)(ws + (708 << 10));            // .5 KB
    float*  f_t = (float*)(ws + ((size_t)17 << 20));     // 16 MB [B][N2][128]
    float*  pd  = (float*)(ws + ((size_t)1 << 20));      // 6.29 MB partials
    int*    pi  = (int*)  (ws + ((size_t)9 << 20));      // 6.29 MB

    prep_kernel<<<320, 256, 0, stream>>>(W0, b0, g0, be0, m0, v0,
                                         W1, b1, g1, be1, m1, v1,
                                         p2, W0p, b0p, W1p, b1p, q4);

    gemm_fused_kernel<<<dim3(32, 8), 256, 0, stream>>>(f2, W0p, b0p,
                                                       W1p, b1p, f_t);

    knn_phase1<<<(NTOT_ / 256) * 4, 256, 0, stream>>>(p1, q4, pd, pi);
    gather_kernel<<<NTOT_ / 64, 256, 0, stream>>>(f_t, pd, pi, (float*)d_out);
}

// Round 10
// 324.153 us; speedup vs baseline: 1.1998x; 1.0031x over previous
//
#include <hip/hip_runtime.h>

#define B_    8
#define N1_   16384
#define N2_   4096
#define NTOT_ (B_ * N1_)

// ---------------------------------------------------------------------------
// GOLD SEMANTICS (verified R12/R13, absmax 0.015625 = bf16 output floor):
//   s  = ((x*x + y*y) + z*z)          plain forward, no fma
//   dot= fma(x,x', fma(y,y', z*z'))   z-first FMA chain (numpy AVX2 einsum)
//   d2 = fma(-2, dot, s1+s2)          bitwise == plain (s1+s2) - 2*dot
//   w  : r = 1/(d2+1e-8), w = r/((r0+r1)+r2), plain f32
// R24: tail budget recalibrated: gemm_fused + gather + gaps ~165us. Three
// additive cuts, knn untouched (proven 154us):
//  (1) gather: merge ONCE (threads 0-63 -> LDS mw/mi), phase-2 reads are
//      uniform-address LDS broadcasts. Removes 96 ds_bpermute/thread and
//      72 redundant global loads/thread. Bit-identical values.
//  (2) BN fold inline in gemm (same fl(W*s)/bias exprs; <=1ulp h diff
//      through relu ~1e-7 << tol; knn selection independent of h).
//  (3) q4 pack absorbed as extra gemm blocks (bx>=256) -> prep dispatch
//      gone; 3 launches total.
// ---------------------------------------------------------------------------
__device__ __forceinline__ float np_sumsq(float x, float y, float z)
{
#pragma clang fp contract(off)
    return ((x * x + y * y) + z * z);   // forward, plain (no contraction)
}

// ---------------------------------------------------------------------------
// FUSED double GEMM + bias + ReLU + q4-pack side role.
// bx in [0,256): per block (batch b = bx>>5, 128 N-cols n0 = (bx&31)*128):
//   phase A: h_tile = relu((W0*s0) @ f2_tile + b0p)   (K=256, global B)
//   phase B: f_t    = relu((W1*s1) @ h_tile + b1p)^T  (K=128, B from LDS)
// BN folds computed inline (identical expressions to the old prep kernel).
// bx in [256,384): q4[t] = (x,y,z,s2) pack for t = (bx-256)*256+tid.
// 128x128 tiles, 8x8 acc; HT head aliases B_lds (B dead before HT write).
// ---------------------------------------------------------------------------
__global__ __launch_bounds__(256) void gemm_fused_kernel(
    const float* __restrict__ f2,
    const float* __restrict__ W0, const float* __restrict__ b0,
    const float* __restrict__ g0, const float* __restrict__ be0,
    const float* __restrict__ m0, const float* __restrict__ v0,
    const float* __restrict__ W1, const float* __restrict__ b1,
    const float* __restrict__ g1, const float* __restrict__ be1,
    const float* __restrict__ m1, const float* __restrict__ v1,
    const float* __restrict__ p2, float4* __restrict__ q4,
    float* __restrict__ f_t)
{
    __shared__ float A_lds[32][136];      // 17.4 KB: A-stage + T
    __shared__ float HT[128][132];        // 67.6 KB: h tile; head aliases B_lds
    float (*B_lds)[128] = (float(*)[128])&HT[0][0];   // [32][128] = 16 KB

    const int tid = threadIdx.x;
    const int bx  = blockIdx.x;

    if (bx >= 256) {                      // ---- q4 pack role ----
        const int t = (bx - 256) * 256 + tid;   // < 32768 exactly
        const float x = p2[3 * (size_t)t + 0];
        const float y = p2[3 * (size_t)t + 1];
        const float z = p2[3 * (size_t)t + 2];
        q4[t] = make_float4(x, y, z, np_sumsq(x, y, z));
        return;
    }

    const int b  = bx >> 5;
    const int n0 = (bx & 31) * 128;
    const int ty = tid >> 4;
    const int tx = tid & 15;

    float acc[8][8];

    // staging assignments (verbatim proven kernel)
    const int a_kq = (tid & 7) * 4;      // k quad within 32
    const int a_r0 = tid >> 3;           // A row base, +32 per i
    const int b_n4 = (tid & 31) * 4;     // n quad (32 thr = 512B/row)
    const int b_k0 = tid >> 5;           // k row base, +8 per i

    // inline BN fold scales for the 4 A-rows this thread stages
    // (identical expression to old prep: g/sqrtf(v+1e-5))
    float s0w[4], s1w[4];
#pragma unroll
    for (int i = 0; i < 4; ++i) {
        const int row = a_r0 + 32 * i;
        s0w[i] = g0[row] / sqrtf(v0[row] + 1e-5f);
        s1w[i] = g1[row] / sqrtf(v1[row] + 1e-5f);
    }

    // ================= phase A: h_tile = relu(W0p @ f2 + b0p) =============
#pragma unroll
    for (int i = 0; i < 8; ++i)
#pragma unroll
        for (int j = 0; j < 8; ++j) acc[i][j] = 0.f;

    {
        const float* Xb = f2 + (size_t)b * 256 * N2_;
        for (int k0 = 0; k0 < 256; k0 += 32) {
#pragma unroll
            for (int i = 0; i < 4; ++i) {
                const int row = a_r0 + 32 * i;
                const float4 v = *(const float4*)&W0[(size_t)row * 256 + k0 + a_kq];
                const float s = s0w[i];
                A_lds[a_kq + 0][row] = v.x * s;
                A_lds[a_kq + 1][row] = v.y * s;
                A_lds[a_kq + 2][row] = v.z * s;
                A_lds[a_kq + 3][row] = v.w * s;
            }
#pragma unroll
            for (int i = 0; i < 4; ++i) {
                const int krow = b_k0 + 8 * i;
                *(float4*)&B_lds[krow][b_n4] =
                    *(const float4*)&Xb[(size_t)(k0 + krow) * N2_ + n0 + b_n4];
            }
            __syncthreads();

#pragma unroll
            for (int kk = 0; kk < 32; ++kk) {
                const float4 a0 = *(const float4*)&A_lds[kk][ty * 4];
                const float4 a1 = *(const float4*)&A_lds[kk][64 + ty * 4];
                const float4 bq0 = *(const float4*)&B_lds[kk][tx * 4];
                const float4 bq1 = *(const float4*)&B_lds[kk][64 + tx * 4];
                const float av[8] = {a0.x, a0.y, a0.z, a0.w, a1.x, a1.y, a1.z, a1.w};
                const float bv[8] = {bq0.x, bq0.y, bq0.z, bq0.w, bq1.x, bq1.y, bq1.z, bq1.w};
#pragma unroll
                for (int i = 0; i < 8; ++i)
#pragma unroll
                    for (int j = 0; j < 8; ++j)
                        acc[i][j] = fmaf(av[i], bv[j], acc[i][j]);
            }
            __syncthreads();
        }
    }

    // h epilogue -> LDS (inline bias fold + relu)
    {
#pragma unroll
        for (int i = 0; i < 8; ++i) {
            const int r = (i < 4) ? (ty * 4 + i) : (64 + ty * 4 + (i - 4));
            const float s = g0[r] / sqrtf(v0[r] + 1e-5f);
            const float bias_v = be0[r] + (b0[r] - m0[r]) * s;
            float4 v0q, v1q;
            v0q.x = fmaxf(acc[i][0] + bias_v, 0.f);
            v0q.y = fmaxf(acc[i][1] + bias_v, 0.f);
            v0q.z = fmaxf(acc[i][2] + bias_v, 0.f);
            v0q.w = fmaxf(acc[i][3] + bias_v, 0.f);
            v1q.x = fmaxf(acc[i][4] + bias_v, 0.f);
            v1q.y = fmaxf(acc[i][5] + bias_v, 0.f);
            v1q.z = fmaxf(acc[i][6] + bias_v, 0.f);
            v1q.w = fmaxf(acc[i][7] + bias_v, 0.f);
            *(float4*)&HT[r][tx * 4] = v0q;
            *(float4*)&HT[r][64 + tx * 4] = v1q;
        }
    }
    // NOTE: first phase-B barrier below guards HT.

    // ================= phase B: out = relu(W1p @ h_tile + b1p) ============
#pragma unroll
    for (int i = 0; i < 8; ++i)
#pragma unroll
        for (int j = 0; j < 8; ++j) acc[i][j] = 0.f;

    for (int k0 = 0; k0 < 128; k0 += 32) {
#pragma unroll
        for (int i = 0; i < 4; ++i) {
            const int row = a_r0 + 32 * i;
            const float4 v = *(const float4*)&W1[(size_t)row * 128 + k0 + a_kq];
            const float s = s1w[i];
            A_lds[a_kq + 0][row] = v.x * s;
            A_lds[a_kq + 1][row] = v.y * s;
            A_lds[a_kq + 2][row] = v.z * s;
            A_lds[a_kq + 3][row] = v.w * s;
        }
        __syncthreads();   // guards HT writes (k0=0) + A_lds staging

#pragma unroll
        for (int kk = 0; kk < 32; ++kk) {
            const float4 a0 = *(const float4*)&A_lds[kk][ty * 4];
            const float4 a1 = *(const float4*)&A_lds[kk][64 + ty * 4];
            const float4 bq0 = *(const float4*)&HT[k0 + kk][tx * 4];
            const float4 bq1 = *(const float4*)&HT[k0 + kk][64 + tx * 4];
            const float av[8] = {a0.x, a0.y, a0.z, a0.w, a1.x, a1.y, a1.z, a1.w};
            const float bv[8] = {bq0.x, bq0.y, bq0.z, bq0.w, bq1.x, bq1.y, bq1.z, bq1.w};
#pragma unroll
            for (int i = 0; i < 8; ++i)
#pragma unroll
                for (int j = 0; j < 8; ++j)
                    acc[i][j] = fmaf(av[i], bv[j], acc[i][j]);
        }
        __syncthreads();
    }

    // TRANS epilogue (verbatim proven): 4 slabs of 32 points; 512B rows.
    {
        float bias_v[8];
#pragma unroll
        for (int i = 0; i < 8; ++i) {
            const int r = (i < 4) ? (ty * 4 + i) : (64 + ty * 4 + (i - 4));
            const float s = g1[r] / sqrtf(v1[r] + 1e-5f);
            bias_v[i] = be1[r] + (b1[r] - m1[r]) * s;
        }
        float (*T)[132] = (float(*)[132])&A_lds[0][0];   // 32x132 <= 32x136
#pragma unroll
        for (int s = 0; s < 4; ++s) {
            if ((tx >> 3) == (s & 1)) {
                const int joff = (s >> 1) * 4;
                const int cl0 = (tx & 7) * 4;
#pragma unroll
                for (int i = 0; i < 8; ++i) {
                    const int r = (i < 4) ? (ty * 4 + i) : (64 + ty * 4 + (i - 4));
#pragma unroll
                    for (int j = 0; j < 4; ++j)
                        T[cl0 + j][r] = fmaxf(acc[i][j + joff] + bias_v[i], 0.f);
                }
            }
            __syncthreads();
#pragma unroll
            for (int p = 0; p < 4; ++p) {
                const int row = (tid >> 5) + 8 * p;
                const float4 v = *(const float4*)&T[row][(tid & 31) * 4];
                float* orow = f_t + ((size_t)b * N2_ + n0 + 32 * s + row) * 128;
                *(float4*)&orow[(tid & 31) * 4] = v;
            }
            __syncthreads();
        }
    }
}

// ---------------------------------------------------------------------------
// KNN phase 1 (R0 verbatim, proven 155.5us @105% VALUBusy): block = 256
// queries x 1 chunk of 1024 candidates; gold d2 scan key; top-3, strict <
// (stable ties, ascending j). Partials out, chunk-major.
// ---------------------------------------------------------------------------
__global__ __launch_bounds__(256, 8) void knn_phase1(
    const float* __restrict__ p1, const float4* __restrict__ q4,
    float* __restrict__ part_d, int* __restrict__ part_i)
{
    __shared__ float4 qs[1024];           // 16 KB
    const int tid = threadIdx.x;
    const int chunk = blockIdx.x & 3;
    const int g = (blockIdx.x >> 2) * 256 + tid;   // query id
    const int b = g >> 14;                         // uniform per block

    const float px = p1[3 * (size_t)g + 0];
    const float py = p1[3 * (size_t)g + 1];
    const float pz = p1[3 * (size_t)g + 2];
    const float s1 = np_sumsq(px, py, pz);

    const float4* qb = q4 + (size_t)b * N2_ + chunk * 1024;
#pragma unroll
    for (int i = 0; i < 4; ++i) qs[tid + i * 256] = qb[tid + i * 256];
    __syncthreads();

    float d0 = 1e30f, d1 = 1e30f, d2v = 1e30f;
    int i0 = 0, i1 = 0, i2 = 0;
    const int jbase = chunk * 1024;

    for (int j = 0; j < 1024; j += 4) {
#pragma unroll
        for (int u = 0; u < 4; ++u) {
            const float4 q = qs[j + u];
            const float dot = __fmaf_rn(px, q.x, __fmaf_rn(py, q.y, __fmul_rn(pz, q.z)));
            const float ss  = s1 + q.w;
            const float t   = __fmaf_rn(-2.0f, dot, ss);
            if (t < d2v) {
                const int jj = jbase + j + u;
                const bool c1 = t < d1, c0 = t < d0;
                d2v = c1 ? d1 : t;                 i2 = c1 ? i1 : jj;
                const float nd1 = c1 ? (c0 ? d0 : t) : d1;
                const int   ni1 = c1 ? (c0 ? i0 : jj) : i1;
                d1 = nd1;                          i1 = ni1;
                d0 = c0 ? t : d0;                  i0 = c0 ? jj : i0;
            }
        }
    }

    part_d[(0 * 4 + chunk) * NTOT_ + g] = d0;
    part_d[(1 * 4 + chunk) * NTOT_ + g] = d1;
    part_d[(2 * 4 + chunk) * NTOT_ + g] = d2v;
    part_i[(0 * 4 + chunk) * NTOT_ + g] = i0;
    part_i[(1 * 4 + chunk) * NTOT_ + g] = i1;
    part_i[(2 * 4 + chunk) * NTOT_ + g] = i2;
}

// ---------------------------------------------------------------------------
// COALESCED gather v2: block = 64 queries (4 waves).
//  1) threads 0-63 merge the 12 chunk partials for query gbase+tid
//     (bit-identical gold order + plain-f32 weights) -> LDS mw/mi.
//     No redundant work, no bpermutes.
//  2) accumulate: wave wv owns queries q=16wv..16wv+15; per j the (w,i)
//     come from uniform-address LDS broadcasts; 64 lanes read float2 of
//     ONE f_t row per instr (512B contiguous); T[64][129] transpose.
//  3) coalesced 256B nontemporal channel-row stores.
// XCD-aligned swizzle: vb = (bx&7)*256 + (bx>>3) (batch <-> XCD).
// ---------------------------------------------------------------------------
__global__ __launch_bounds__(256) void gather_kernel(
    const float* __restrict__ f_t, const float* __restrict__ part_d,
    const int* __restrict__ part_i, float* __restrict__ out)
{
    __shared__ float T[64][129];          // 33 KB
    __shared__ float mw[3][64];
    __shared__ int   mi[3][64];
    const int tid = threadIdx.x;
    const int lane = tid & 63, wv = tid >> 6;
    const int vb = (blockIdx.x & 7) * 256 + (blockIdx.x >> 3);  // bijective
    const int gbase = vb * 64;
    const int b = gbase >> 14, n0 = gbase & 16383;

    if (tid < 64) {
        const int g = gbase + tid;
        // stable 12-way merge (chunk-major preserves gold tie order)
        float d0 = 1e30f, d1 = 1e30f, d2v = 1e30f;
        int i0 = 0, i1 = 0, i2 = 0;
#pragma unroll
        for (int c = 0; c < 4; ++c) {
#pragma unroll
            for (int k = 0; k < 3; ++k) {
                const float t = part_d[(k * 4 + c) * NTOT_ + g];
                const int  jj = part_i[(k * 4 + c) * NTOT_ + g];
                if (t < d2v) {
                    const bool c1 = t < d1, c0 = t < d0;
                    d2v = c1 ? d1 : t;                 i2 = c1 ? i1 : jj;
                    const float nd1 = c1 ? (c0 ? d0 : t) : d1;
                    const int   ni1 = c1 ? (c0 ? i0 : jj) : i1;
                    d1 = nd1;                          i1 = ni1;
                    d0 = c0 ? t : d0;                  i0 = c0 ? jj : i0;
                }
            }
        }
        float w0, w1, w2;
        {
#pragma clang fp contract(off)
            const float r0 = 1.0f / (d0 + 1e-8f);
            const float r1 = 1.0f / (d1 + 1e-8f);
            const float r2 = 1.0f / (d2v + 1e-8f);
            const float rs = (r0 + r1) + r2;
            w0 = r0 / rs;
            w1 = r1 / rs;
            w2 = r2 / rs;
        }
        mw[0][tid] = w0;  mw[1][tid] = w1;  mw[2][tid] = w2;
        mi[0][tid] = i0;  mi[1][tid] = i1;  mi[2][tid] = i2;
    }
    __syncthreads();

    // ---- 2) accumulate: wave wv owns queries q = 16*wv .. 16*wv+15 ----
    const float* fb = f_t + (size_t)b * N2_ * 128;
#pragma unroll
    for (int j = 0; j < 16; ++j) {
        const int q = wv * 16 + j;
        const int   qi0 = mi[0][q];              // uniform -> LDS broadcast
        const int   qi1 = mi[1][q];
        const int   qi2 = mi[2][q];
        const float qw0 = mw[0][q];
        const float qw1 = mw[1][q];
        const float qw2 = mw[2][q];
        const float2 a  = *(const float2*)(fb + (size_t)qi0 * 128 + 2 * lane);
        const float2 bb = *(const float2*)(fb + (size_t)qi1 * 128 + 2 * lane);
        const float2 c  = *(const float2*)(fb + (size_t)qi2 * 128 + 2 * lane);
        T[q][2 * lane + 0] = fmaf(qw0, a.x, fmaf(qw1, bb.x, qw2 * c.x));
        T[q][2 * lane + 1] = fmaf(qw0, a.y, fmaf(qw1, bb.y, qw2 * c.y));
    }
    __syncthreads();

    // ---- 3) transpose store: wave wv -> channels 32*wv .. 32*wv+31 ----
    float* ob = out + ((size_t)b * 128) * N1_ + n0 + lane;
#pragma unroll
    for (int ci = 0; ci < 32; ++ci) {
        const int cch = wv * 32 + ci;
        __builtin_nontemporal_store(T[lane][cch], ob + (size_t)cch * N1_);
    }
}

// ---------------------------------------------------------------------------
extern "C" void kernel_launch(void* const* d_in, const int* in_sizes, int n_in,
                              void* d_out, int out_size, void* d_ws, size_t ws_size,
                              hipStream_t stream)
{
    const float* p1  = (const float*)d_in[0];
    const float* p2  = (const float*)d_in[1];
    const float* f2  = (const float*)d_in[2];
    const float* W0  = (const float*)d_in[3];
    const float* b0  = (const float*)d_in[4];
    const float* g0  = (const float*)d_in[5];
    const float* be0 = (const float*)d_in[6];
    const float* m0  = (const float*)d_in[7];
    const float* v0  = (const float*)d_in[8];
    const float* W1  = (const float*)d_in[9];
    const float* b1  = (const float*)d_in[10];
    const float* g1  = (const float*)d_in[11];
    const float* be1 = (const float*)d_in[12];
    const float* m1  = (const float*)d_in[13];
    const float* v1  = (const float*)d_in[14];

    char* ws = (char*)d_ws;
    float4* q4  = (float4*)(ws);                         // 512 KB
    float*  f_t = (float*)(ws + ((size_t)17 << 20));     // 16 MB [B][N2][128]
    float*  pd  = (float*)(ws + ((size_t)1 << 20));      // 6.29 MB partials
    int*    pi  = (int*)  (ws + ((size_t)9 << 20));      // 6.29 MB

    gemm_fused_kernel<<<384, 256, 0, stream>>>(f2,
                                               W0, b0, g0, be0, m0, v0,
                                               W1, b1, g1, be1, m1, v1,
                                               p2, q4, f_t);

    knn_phase1<<<(NTOT_ / 256) * 4, 256, 0, stream>>>(p1, q4, pd, pi);
    gather_kernel<<<NTOT_ / 64, 256, 0, stream>>>(f_t, pd, pi, (float*)d_out);
}